// Round 9
// baseline (467.583 us; speedup 1.0000x reference)
//
#include <hip/hip_runtime.h>
#include <stdint.h>

typedef unsigned short u16;
typedef unsigned int   u32;
typedef __attribute__((ext_vector_type(8))) short short8;
typedef __attribute__((ext_vector_type(4))) float f32x4;

#define CHUNK 8192   // edges per block in hist/scatter phases

__device__ __forceinline__ u16 f2bf(float f) {
    u32 u = __float_as_uint(f);
    u32 r = (u + 0x7FFFu + ((u >> 16) & 1u)) >> 16;   // RNE
    return (u16)r;
}

// int64-stored-raw edge_index has every high 32-bit word zero (vals < 2^17).
__device__ __forceinline__ int edge_is64(const int* __restrict__ ei) {
    return ((ei[1] | ei[3] | ei[5] | ei[7] | ei[9] | ei[11]) == 0) ? 1 : 0;
}

__global__ void zero_out(float* __restrict__ p, size_t n) {
    size_t i = (size_t)blockIdx.x * 256 + threadIdx.x;
    size_t stride = (size_t)gridDim.x * 256;
    for (; i < n; i += stride) p[i] = 0.f;
}

// ---------------------------------------------------------------------------
// Phase 1: per-block histogram over coarse buckets (dst >> 8).
// ---------------------------------------------------------------------------
__global__ void hist_bucket(const int* __restrict__ ei, int* __restrict__ cnt,
                            int E, int N, int nb, int NBK) {
    __shared__ int h[256];
    int b = blockIdx.x, t = threadIdx.x;
    h[t] = 0;
    __syncthreads();
    int is64 = edge_is64(ei);
    int base = b * CHUNK;
    int endE = min(base + CHUNK, E);
    for (int i = base + t; i < endE; i += 256) {
        int dst = is64 ? ei[2 * E + 2 * i] : ei[E + i];
        dst = min(max(dst, 0), N - 1);
        atomicAdd(&h[dst >> 8], 1);
    }
    __syncthreads();
    for (int B = t; B < NBK; B += 256) cnt[B * nb + b] = h[B];
}

// ---------------------------------------------------------------------------
// Hierarchical exclusive scan (in place) over int array a[M].
// ---------------------------------------------------------------------------
__global__ void scan_partial(const int* __restrict__ a, int* __restrict__ bsum, int M) {
    __shared__ int sh[256];
    int t = threadIdx.x;
    int idx0 = blockIdx.x * 1024 + t * 4;
    int s = 0;
    #pragma unroll
    for (int i = 0; i < 4; ++i) { int idx = idx0 + i; if (idx < M) s += a[idx]; }
    sh[t] = s;
    __syncthreads();
    #pragma unroll
    for (int off = 128; off > 0; off >>= 1) {
        if (t < off) sh[t] += sh[t + off];
        __syncthreads();
    }
    if (t == 0) bsum[blockIdx.x] = sh[0];
}

__global__ void scan_bsum(int* __restrict__ bsum, int nbs) {
    __shared__ int sh[256];
    __shared__ int carry;
    int t = threadIdx.x;
    if (t == 0) carry = 0;
    __syncthreads();
    for (int base = 0; base < nbs; base += 256) {
        int v = (base + t < nbs) ? bsum[base + t] : 0;
        sh[t] = v;
        __syncthreads();
        #pragma unroll
        for (int off = 1; off < 256; off <<= 1) {
            int x = (t >= off) ? sh[t - off] : 0;
            __syncthreads();
            sh[t] += x;
            __syncthreads();
        }
        if (base + t < nbs) bsum[base + t] = carry + sh[t] - v;
        __syncthreads();
        if (t == 255) carry += sh[255];
        __syncthreads();
    }
}

__global__ void scan_final(int* __restrict__ a, const int* __restrict__ bsum, int M) {
    __shared__ int sh[256];
    int t = threadIdx.x;
    int idx0 = blockIdx.x * 1024 + t * 4;
    int v[4];
    int s = 0;
    #pragma unroll
    for (int i = 0; i < 4; ++i) {
        int idx = idx0 + i;
        v[i] = (idx < M) ? a[idx] : 0;
        s += v[i];
    }
    sh[t] = s;
    __syncthreads();
    #pragma unroll
    for (int off = 1; off < 256; off <<= 1) {
        int x = (t >= off) ? sh[t - off] : 0;
        __syncthreads();
        sh[t] += x;
        __syncthreads();
    }
    int run = sh[t] - s + bsum[blockIdx.x];
    #pragma unroll
    for (int i = 0; i < 4; ++i) {
        int idx = idx0 + i;
        if (idx < M) a[idx] = run;
        run += v[i];
    }
}

// ---------------------------------------------------------------------------
// Phase 3: scatter packed edges (src | (dst&255)<<17) into per-(block,bucket)
// exclusive regions. LDS cursors -> dense block-private global writes.
// ---------------------------------------------------------------------------
__global__ void scatter_pairs(const int* __restrict__ ei, const int* __restrict__ pboff,
                              u32* __restrict__ pairs, int E, int N, int nb, int NBK) {
    __shared__ int cur[256];
    int b = blockIdx.x, t = threadIdx.x;
    for (int B = t; B < NBK; B += 256) cur[B] = pboff[B * nb + b];
    __syncthreads();
    int is64 = edge_is64(ei);
    int base = b * CHUNK;
    int endE = min(base + CHUNK, E);
    for (int i = base + t; i < endE; i += 256) {
        int src = is64 ? ei[2 * i] : ei[i];
        int dst = is64 ? ei[2 * E + 2 * i] : ei[E + i];
        src = min(max(src, 0), N - 1);
        dst = min(max(dst, 0), N - 1);
        int slot = atomicAdd(&cur[dst >> 8], 1);
        pairs[slot] = (u32)src | ((u32)(dst & 255) << 17);
    }
}

// ---------------------------------------------------------------------------
// Phase 4: per-bucket counting sort (256 nodes). Writes offs[] and CSR ssrc.
// ---------------------------------------------------------------------------
__global__ void fine_sort(const u32* __restrict__ pairs, const int* __restrict__ pboff,
                          int* __restrict__ offs, int* __restrict__ ssrc,
                          int E, int N, int nb, int NBK) {
    __shared__ int hist[256];
    __shared__ int excl[256];
    __shared__ int cur[256];
    int B = blockIdx.x, t = threadIdx.x;
    if (B == 0 && t == 0) offs[N] = E;
    int rs = pboff[B * nb];
    int re = (B + 1 < NBK) ? pboff[(B + 1) * nb] : E;
    hist[t] = 0;
    __syncthreads();
    for (int i = rs + t; i < re; i += 256) {
        u32 p = pairs[i];
        atomicAdd(&hist[(p >> 17) & 255], 1);
    }
    __syncthreads();
    int v = hist[t];
    excl[t] = v;
    __syncthreads();
    #pragma unroll
    for (int off = 1; off < 256; off <<= 1) {
        int x = (t >= off) ? excl[t - off] : 0;
        __syncthreads();
        excl[t] += x;
        __syncthreads();
    }
    int ex = excl[t] - v;
    int node = B * 256 + t;
    if (node < N) offs[node] = rs + ex;
    cur[t] = rs + ex;
    __syncthreads();
    for (int i = rs + t; i < re; i += 256) {
        u32 p = pairs[i];
        int slot = atomicAdd(&cur[(p >> 17) & 255], 1);
        ssrc[slot] = (int)(p & 0x1FFFFu);
    }
}

// ---------------------------------------------------------------------------
// dtype prep: x->bf16 conversion and weight concat+convert, merged into one
// dispatch (independent work; saves a launch).
// ---------------------------------------------------------------------------
__global__ void prep_all(const float4* __restrict__ x, uint2* __restrict__ H, int n4,
                         const float* __restrict__ Wl0, const float* __restrict__ Wr0,
                         const float* __restrict__ Wl1, const float* __restrict__ Wr1,
                         const float* __restrict__ Wl2, const float* __restrict__ Wr2,
                         u16* __restrict__ Wc0, u16* __restrict__ Wc1,
                         u16* __restrict__ Wc2) {
    int i = blockIdx.x * 256 + threadIdx.x;
    if (i < n4) {
        float4 v = x[i];
        uint2 o;
        o.x = ((u32)f2bf(v.y) << 16) | f2bf(v.x);
        o.y = ((u32)f2bf(v.w) << 16) | f2bf(v.z);
        H[i] = o;
        return;
    }
    int k = i - n4;                      // 0 .. 131071 weight elems
    if (k >= 131072) return;
    const float* Wl; const float* Wr; u16* Wc; int base;
    if (k < 32768)      { Wl = Wl0; Wr = Wr0; Wc = Wc0; base = k; }
    else if (k < 65536) { Wl = Wl1; Wr = Wr1; Wc = Wc1; base = k - 32768; }
    else                { Wl = Wl2; Wr = Wr2; Wc = Wc2; base = k - 65536; }
    int j = base >> 8, kk = base & 255;
    float v = (kk < 128) ? Wl[j * 128 + kk] : Wr[j * 128 + (kk - 128)];
    Wc[base] = f2bf(v);
}

__device__ __forceinline__ void acc8(float* a, uint4 p) {
    a[0] += __uint_as_float(p.x << 16); a[1] += __uint_as_float(p.x & 0xFFFF0000u);
    a[2] += __uint_as_float(p.y << 16); a[3] += __uint_as_float(p.y & 0xFFFF0000u);
    a[4] += __uint_as_float(p.z << 16); a[5] += __uint_as_float(p.z & 0xFFFF0000u);
    a[6] += __uint_as_float(p.w << 16); a[7] += __uint_as_float(p.w & 0xFFFF0000u);
}

// ---------------------------------------------------------------------------
// FUSED layer kernel (round-8 resubmit; round-8 bench was an infra failure,
// not a kernel result). Per-wave MLP in the gather is not winnable from HIP
// source (4 attempts, VGPR pinned at 48 by the pressure scheduler). The
// remaining concurrency lever is WAVE COUNT: __launch_bounds__(256,8)
// (VGPR cap 64 > 48 in use, no spill expected) -> 8 blocks/CU (LDS 16.9 KB
// x 8 = 135 KB < 160), 32 waves/CU vs 16 — ~2x the resident waves issuing
// gather loads. Everything else unchanged from round 7.
// ---------------------------------------------------------------------------
template<int DOUT, bool RELU, bool OUT_F32, bool WRITE_MEAN>
__global__ __launch_bounds__(256, 8)
void fused_gemm(const u16* __restrict__ H, const int* __restrict__ offs,
                const int* __restrict__ ssrc, const u16* __restrict__ Wc,
                const float* __restrict__ bias, void* __restrict__ out,
                u16* __restrict__ Mb, int N) {
    constexpr int OSMB = OUT_F32 ? (32 * 132 * 4) : (32 * 136 * 2);
    constexpr int ASMB = 2 * 32 * 128 * 2;                // 16 KB A-tile
    constexpr int SMB  = (ASMB > OSMB) ? ASMB : OSMB;
    __shared__ __align__(16) char smem[SMB];
    u16* ldsA0 = (u16*)smem;               // mean half
    u16* ldsA1 = (u16*)smem + 32 * 128;    // H half

    int tid = threadIdx.x;
    int w   = tid >> 6;               // wave id 0..3 -> 32-col slice
    int l   = tid & 63;
    int lr  = l & 15;
    int lq  = l >> 4;
    int kof = lq * 8;

    int mb0 = blockIdx.x * 32;        // row tile base
    int nc  = w * 32;                 // this wave's col base (slab-relative)

    // ---- (1) H-tile DMA into ldsA1: fire-and-forget, overlaps gather ----
    {
        const u16* gH = H + (size_t)mb0 * 128;   // 8 KB contiguous
        #pragma unroll
        for (int p = 0; p < 2; ++p) {
            int c  = p * 256 + tid;              // LDS chunk 0..511 (16 B units)
            int r  = c >> 4;                     // row 0..31
            int jj = c & 15;                     // LDS chunk-in-row
            int gj = jj ^ (r & 15);              // inverse-swizzled global chunk
            __builtin_amdgcn_global_load_lds(
                (const u32*)(gH + (size_t)(r * 16 + gj) * 8),
                (u32*)(ldsA1 + (size_t)c * 8), 16, 0, 0);
        }
    }

    // ---- (2) gather-aggregate: dual-node interleaved cursors ----
    {
        int g   = tid >> 4;           // group 0..15
        int sub = tid & 15;           // 8 dims per lane
        int nA  = mb0 + g;            // local row g
        int nB  = nA + 16;            // local row g+16
        int jA = 0, eA = 0, jB = 0, eB = 0;
        if (nA < N) { jA = offs[nA]; eA = offs[nA + 1]; }
        if (nB < N) { jB = offs[nB]; eB = offs[nB + 1]; }
        int dA = eA - jA, dB = eB - jB;
        float aA[8] = {}, aB[8] = {};

        while (jA + 4 <= eA && jB + 4 <= eB) {
            int sA0 = ssrc[jA], sA1 = ssrc[jA + 1], sA2 = ssrc[jA + 2], sA3 = ssrc[jA + 3];
            int sB0 = ssrc[jB], sB1 = ssrc[jB + 1], sB2 = ssrc[jB + 2], sB3 = ssrc[jB + 3];
            uint4 pA0 = *(const uint4*)(H + (size_t)sA0 * 128 + sub * 8);
            uint4 pA1 = *(const uint4*)(H + (size_t)sA1 * 128 + sub * 8);
            uint4 pA2 = *(const uint4*)(H + (size_t)sA2 * 128 + sub * 8);
            uint4 pA3 = *(const uint4*)(H + (size_t)sA3 * 128 + sub * 8);
            uint4 pB0 = *(const uint4*)(H + (size_t)sB0 * 128 + sub * 8);
            uint4 pB1 = *(const uint4*)(H + (size_t)sB1 * 128 + sub * 8);
            uint4 pB2 = *(const uint4*)(H + (size_t)sB2 * 128 + sub * 8);
            uint4 pB3 = *(const uint4*)(H + (size_t)sB3 * 128 + sub * 8);
            acc8(aA, pA0); acc8(aB, pB0);
            acc8(aA, pA1); acc8(aB, pB1);
            acc8(aA, pA2); acc8(aB, pB2);
            acc8(aA, pA3); acc8(aB, pB3);
            jA += 4; jB += 4;
        }
        for (; jA + 4 <= eA; jA += 4) {
            int s0 = ssrc[jA], s1 = ssrc[jA + 1], s2 = ssrc[jA + 2], s3 = ssrc[jA + 3];
            uint4 p0 = *(const uint4*)(H + (size_t)s0 * 128 + sub * 8);
            uint4 p1 = *(const uint4*)(H + (size_t)s1 * 128 + sub * 8);
            uint4 p2 = *(const uint4*)(H + (size_t)s2 * 128 + sub * 8);
            uint4 p3 = *(const uint4*)(H + (size_t)s3 * 128 + sub * 8);
            acc8(aA, p0); acc8(aA, p1); acc8(aA, p2); acc8(aA, p3);
        }
        for (; jA < eA; ++jA) {
            uint4 p0 = *(const uint4*)(H + (size_t)ssrc[jA] * 128 + sub * 8);
            acc8(aA, p0);
        }
        for (; jB + 4 <= eB; jB += 4) {
            int s0 = ssrc[jB], s1 = ssrc[jB + 1], s2 = ssrc[jB + 2], s3 = ssrc[jB + 3];
            uint4 p0 = *(const uint4*)(H + (size_t)s0 * 128 + sub * 8);
            uint4 p1 = *(const uint4*)(H + (size_t)s1 * 128 + sub * 8);
            uint4 p2 = *(const uint4*)(H + (size_t)s2 * 128 + sub * 8);
            uint4 p3 = *(const uint4*)(H + (size_t)s3 * 128 + sub * 8);
            acc8(aB, p0); acc8(aB, p1); acc8(aB, p2); acc8(aB, p3);
        }
        for (; jB < eB; ++jB) {
            uint4 p0 = *(const uint4*)(H + (size_t)ssrc[jB] * 128 + sub * 8);
            acc8(aB, p0);
        }

        if (nA < N) {
            float sc = 1.f / (float)(dA > 0 ? dA : 1);
            #pragma unroll
            for (int i = 0; i < 8; ++i) aA[i] *= sc;
            uint4 o;
            o.x = ((u32)f2bf(aA[1]) << 16) | f2bf(aA[0]);
            o.y = ((u32)f2bf(aA[3]) << 16) | f2bf(aA[2]);
            o.z = ((u32)f2bf(aA[5]) << 16) | f2bf(aA[4]);
            o.w = ((u32)f2bf(aA[7]) << 16) | f2bf(aA[6]);
            int jx = sub ^ (g & 15);
            *(uint4*)(ldsA0 + ((size_t)g * 16 + jx) * 8) = o;
            if (WRITE_MEAN)
                *(uint4*)(Mb + (size_t)nA * 128 + sub * 8) = o;
        }
        if (nB < N) {
            float sc = 1.f / (float)(dB > 0 ? dB : 1);
            #pragma unroll
            for (int i = 0; i < 8; ++i) aB[i] *= sc;
            uint4 o;
            o.x = ((u32)f2bf(aB[1]) << 16) | f2bf(aB[0]);
            o.y = ((u32)f2bf(aB[3]) << 16) | f2bf(aB[2]);
            o.z = ((u32)f2bf(aB[5]) << 16) | f2bf(aB[4]);
            o.w = ((u32)f2bf(aB[7]) << 16) | f2bf(aB[6]);
            int r  = g + 16;
            int jx = sub ^ (r & 15);
            *(uint4*)(ldsA0 + ((size_t)r * 16 + jx) * 8) = o;
            if (WRITE_MEAN)
                *(uint4*)(Mb + (size_t)nB * 128 + sub * 8) = o;
        }
    }

    // ---- (3) B panel into registers (L2-resident, short liveness) ----
    short8 b0[8], b1[8];
    #pragma unroll
    for (int ks = 0; ks < 8; ++ks) {
        int kb = ks * 32 + kof;
        b0[ks] = *(const short8*)(Wc + (size_t)(nc + lr) * 256 + kb);
        b1[ks] = *(const short8*)(Wc + (size_t)(nc + 16 + lr) * 256 + kb);
    }
    float bv0 = bias[nc + lr];
    float bv1 = bias[nc + 16 + lr];

    __syncthreads();   // drains DMA (vmcnt) + mean ds_writes (lgkm)

    // ---- (4) MFMA: A frags from LDS (swizzled), B from regs ----
    f32x4 acc[2][2];
    #pragma unroll
    for (int i = 0; i < 2; ++i)
        #pragma unroll
        for (int j = 0; j < 2; ++j) acc[i][j] = (f32x4){0.f, 0.f, 0.f, 0.f};

    #pragma unroll
    for (int ks = 0; ks < 8; ++ks) {
        const u16* hb = (ks < 4) ? ldsA0 : ldsA1;
        int j0 = (ks & 3) * 4 + lq;              // chunk-in-row this frag needs
        int jx = j0 ^ lr;                        // swizzled LDS chunk
        short8 a0 = *(const short8*)(hb + ((size_t)lr * 16 + jx) * 8);
        short8 a1 = *(const short8*)(hb + ((size_t)(lr + 16) * 16 + jx) * 8);
        acc[0][0] = __builtin_amdgcn_mfma_f32_16x16x32_bf16(a0, b0[ks], acc[0][0], 0, 0, 0);
        acc[0][1] = __builtin_amdgcn_mfma_f32_16x16x32_bf16(a0, b1[ks], acc[0][1], 0, 0, 0);
        acc[1][0] = __builtin_amdgcn_mfma_f32_16x16x32_bf16(a1, b0[ks], acc[1][0], 0, 0, 0);
        acc[1][1] = __builtin_amdgcn_mfma_f32_16x16x32_bf16(a1, b1[ks], acc[1][1], 0, 0, 0);
    }

    __syncthreads();   // A-tile reads done -> safe to reuse smem for epilogue

    // ---- epilogue: bias/relu -> LDS tile (union) -> coalesced stores ----
    if (OUT_F32) {
        float* sm = (float*)smem;                 // [32][132] padded
        #pragma unroll
        for (int ct = 0; ct < 2; ++ct) {
            int cl = w * 32 + ct * 16 + lr;
            float bv = ct ? bv1 : bv0;
            #pragma unroll
            for (int rg = 0; rg < 2; ++rg) {
                #pragma unroll
                for (int i = 0; i < 4; ++i) {
                    int rl = rg * 16 + lq * 4 + i;
                    float v = acc[rg][ct][i] + bv;
                    if (RELU) v = fmaxf(v, 0.f);
                    sm[rl * 132 + cl] = v;
                }
            }
        }
        __syncthreads();
        #pragma unroll
        for (int c = 0; c < 4; ++c) {
            int chunk = c * 256 + tid;
            int rr = chunk >> 5, cc = chunk & 31;
            int row = mb0 + rr;
            if (row < N) {
                float4 v = *(const float4*)(sm + rr * 132 + cc * 4);
                *(float4*)((float*)out + (size_t)row * DOUT + cc * 4) = v;
            }
        }
    } else {
        u16* sm = (u16*)smem;                     // [32][136] padded
        #pragma unroll
        for (int ct = 0; ct < 2; ++ct) {
            int cl = w * 32 + ct * 16 + lr;
            float bv = ct ? bv1 : bv0;
            #pragma unroll
            for (int rg = 0; rg < 2; ++rg) {
                #pragma unroll
                for (int i = 0; i < 4; ++i) {
                    int rl = rg * 16 + lq * 4 + i;
                    float v = acc[rg][ct][i] + bv;
                    if (RELU) v = fmaxf(v, 0.f);
                    sm[rl * 136 + cl] = f2bf(v);
                }
            }
        }
        __syncthreads();
        #pragma unroll
        for (int c = 0; c < 2; ++c) {
            int chunk = c * 256 + tid;
            int rr = chunk >> 4, cc = chunk & 15;
            int row = mb0 + rr;
            if (row < N) {
                uint4 v = *(const uint4*)(sm + rr * 136 + cc * 8);
                *(uint4*)((u16*)out + (size_t)row * DOUT + cc * 8) = v;
            }
        }
    }
}

// ---------------------------------------------------------------------------
// Plain MFMA GEMM (round-4 structure + LDS union), used only for layer-2
// cols 128..255: reads the mean from Mb (written once by the fused kernel).
// Kept at (256,4): it holds B across its barrier and is not the bottleneck.
// ---------------------------------------------------------------------------
template<int DOUT, bool RELU, bool OUT_F32>
__global__ __launch_bounds__(256, 4)
void gemm_mfma(const u16* __restrict__ M, const u16* __restrict__ H,
               const u16* __restrict__ Wc, const float* __restrict__ bias,
               void* __restrict__ out, int N, int noff) {
    constexpr int OSMB = OUT_F32 ? (32 * 132 * 4) : (32 * 136 * 2);
    constexpr int ASMB = 2 * 32 * 128 * 2;
    constexpr int SMB  = (ASMB > OSMB) ? ASMB : OSMB;
    __shared__ __align__(16) char smem[SMB];
    u16* ldsA0 = (u16*)smem;
    u16* ldsA1 = (u16*)smem + 32 * 128;

    int tid = threadIdx.x;
    int w   = tid >> 6;
    int l   = tid & 63;
    int lr  = l & 15;
    int lq  = l >> 4;
    int kof = lq * 8;

    int mb0 = blockIdx.x * 32;
    int nc  = w * 32;

    // ---- A-tile DMA into LDS ----
    {
        const u16* gM = M + (size_t)mb0 * 128;
        const u16* gH = H + (size_t)mb0 * 128;
        #pragma unroll
        for (int p = 0; p < 2; ++p) {
            int c  = p * 256 + tid;
            int r  = c >> 4;
            int jj = c & 15;
            int gj = jj ^ (r & 15);
            __builtin_amdgcn_global_load_lds(
                (const u32*)(gM + (size_t)(r * 16 + gj) * 8),
                (u32*)(ldsA0 + (size_t)c * 8), 16, 0, 0);
            __builtin_amdgcn_global_load_lds(
                (const u32*)(gH + (size_t)(r * 16 + gj) * 8),
                (u32*)(ldsA1 + (size_t)c * 8), 16, 0, 0);
        }
    }

    // ---- B panel into registers ----
    short8 b0[8], b1[8];
    #pragma unroll
    for (int ks = 0; ks < 8; ++ks) {
        int kb = ks * 32 + kof;
        b0[ks] = *(const short8*)(Wc + (size_t)(nc + lr) * 256 + kb);
        b1[ks] = *(const short8*)(Wc + (size_t)(nc + 16 + lr) * 256 + kb);
    }
    float bv0 = bias[nc + lr];
    float bv1 = bias[nc + 16 + lr];

    __syncthreads();

    f32x4 acc[2][2];
    #pragma unroll
    for (int i = 0; i < 2; ++i)
        #pragma unroll
        for (int j = 0; j < 2; ++j) acc[i][j] = (f32x4){0.f, 0.f, 0.f, 0.f};

    #pragma unroll
    for (int ks = 0; ks < 8; ++ks) {
        const u16* hb = (ks < 4) ? ldsA0 : ldsA1;
        int j0 = (ks & 3) * 4 + lq;
        int jx = j0 ^ lr;
        short8 a0 = *(const short8*)(hb + ((size_t)lr * 16 + jx) * 8);
        short8 a1 = *(const short8*)(hb + ((size_t)(lr + 16) * 16 + jx) * 8);
        acc[0][0] = __builtin_amdgcn_mfma_f32_16x16x32_bf16(a0, b0[ks], acc[0][0], 0, 0, 0);
        acc[0][1] = __builtin_amdgcn_mfma_f32_16x16x32_bf16(a0, b1[ks], acc[0][1], 0, 0, 0);
        acc[1][0] = __builtin_amdgcn_mfma_f32_16x16x32_bf16(a1, b0[ks], acc[1][0], 0, 0, 0);
        acc[1][1] = __builtin_amdgcn_mfma_f32_16x16x32_bf16(a1, b1[ks], acc[1][1], 0, 0, 0);
    }

    __syncthreads();   // A-tile reads done -> reuse smem for epilogue

    if (OUT_F32) {
        float* sm = (float*)smem;
        #pragma unroll
        for (int ct = 0; ct < 2; ++ct) {
            int cl = w * 32 + ct * 16 + lr;
            float bv = ct ? bv1 : bv0;
            #pragma unroll
            for (int rg = 0; rg < 2; ++rg) {
                #pragma unroll
                for (int i = 0; i < 4; ++i) {
                    int rl = rg * 16 + lq * 4 + i;
                    float v = acc[rg][ct][i] + bv;
                    if (RELU) v = fmaxf(v, 0.f);
                    sm[rl * 132 + cl] = v;
                }
            }
        }
        __syncthreads();
        #pragma unroll
        for (int c = 0; c < 4; ++c) {
            int chunk = c * 256 + tid;
            int rr = chunk >> 5, cc = chunk & 31;
            int row = mb0 + rr;
            if (row < N) {
                float4 v = *(const float4*)(sm + rr * 132 + cc * 4);
                *(float4*)((float*)out + (size_t)row * DOUT + noff + cc * 4) = v;
            }
        }
    } else {
        u16* sm = (u16*)smem;
        #pragma unroll
        for (int ct = 0; ct < 2; ++ct) {
            int cl = w * 32 + ct * 16 + lr;
            float bv = ct ? bv1 : bv0;
            #pragma unroll
            for (int rg = 0; rg < 2; ++rg) {
                #pragma unroll
                for (int i = 0; i < 4; ++i) {
                    int rl = rg * 16 + lq * 4 + i;
                    float v = acc[rg][ct][i] + bv;
                    if (RELU) v = fmaxf(v, 0.f);
                    sm[rl * 136 + cl] = f2bf(v);
                }
            }
        }
        __syncthreads();
        #pragma unroll
        for (int c = 0; c < 2; ++c) {
            int chunk = c * 256 + tid;
            int rr = chunk >> 4, cc = chunk & 15;
            int row = mb0 + rr;
            if (row < N) {
                uint4 v = *(const uint4*)(sm + rr * 136 + cc * 8);
                *(uint4*)((u16*)out + (size_t)row * DOUT + noff + cc * 8) = v;
            }
        }
    }
}

extern "C" void kernel_launch(void* const* d_in, const int* in_sizes, int n_in,
                              void* d_out, int out_size, void* d_ws, size_t ws_size,
                              hipStream_t stream) {
    const float* x   = (const float*)d_in[0];
    const int*   ei  = (const int*)d_in[1];
    const float* Wl0 = (const float*)d_in[2];
    const float* bl0 = (const float*)d_in[3];
    const float* Wr0 = (const float*)d_in[4];
    const float* Wl1 = (const float*)d_in[5];
    const float* bl1 = (const float*)d_in[6];
    const float* Wr1 = (const float*)d_in[7];
    const float* Wl2 = (const float*)d_in[8];
    const float* bl2 = (const float*)d_in[9];
    const float* Wr2 = (const float*)d_in[10];

    const int N = in_sizes[0] / 128;
    const int E = in_sizes[1] / 2;

    const int NBK = (N + 255) >> 8;
    const int nb  = (E + CHUNK - 1) / CHUNK;
    const int M_  = NBK * nb;
    const int nbs = (M_ + 1023) / 1024;

    size_t off = 0;
    auto alloc = [&](size_t bytes) -> size_t {
        size_t p = off;
        off += (bytes + 255) & ~(size_t)255;
        return p;
    };
    size_t o_cnt   = alloc((size_t)M_ * 4);
    size_t o_bsum  = alloc((size_t)nbs * 4);
    size_t o_offs  = alloc(((size_t)N + 1) * 4);
    size_t o_ssrc  = alloc((size_t)E * 4);
    size_t o_pairs = alloc((size_t)E * 4);
    size_t o_Hx    = alloc((size_t)N * 128 * 2);
    size_t o_Ha    = alloc((size_t)N * 128 * 2);
    size_t o_Hb    = alloc((size_t)N * 128 * 2);
    size_t o_Mb    = alloc((size_t)N * 128 * 2);
    size_t o_Wc0   = alloc((size_t)128 * 256 * 2);
    size_t o_Wc1   = alloc((size_t)128 * 256 * 2);
    size_t o_Wc2   = alloc((size_t)256 * 256 * 2);

    if (off > ws_size || NBK > 256 || N > (1 << 17)) {
        zero_out<<<2048, 256, 0, stream>>>((float*)d_out, (size_t)out_size);
        return;
    }

    char* ws = (char*)d_ws;
    int*  cnt   = (int*)(ws + o_cnt);
    int*  bsum  = (int*)(ws + o_bsum);
    int*  offs  = (int*)(ws + o_offs);
    int*  ssrc  = (int*)(ws + o_ssrc);
    u32*  pairs = (u32*)(ws + o_pairs);
    u16*  Hx    = (u16*)(ws + o_Hx);
    u16*  Ha    = (u16*)(ws + o_Ha);
    u16*  Hb    = (u16*)(ws + o_Hb);
    u16*  Mb    = (u16*)(ws + o_Mb);
    u16*  Wc0   = (u16*)(ws + o_Wc0);
    u16*  Wc1   = (u16*)(ws + o_Wc1);
    u16*  Wc2   = (u16*)(ws + o_Wc2);

    // CSR build: hist -> scan -> block-private scatter -> per-bucket sort
    hist_bucket<<<nb, 256, 0, stream>>>(ei, cnt, E, N, nb, NBK);
    scan_partial<<<nbs, 256, 0, stream>>>(cnt, bsum, M_);
    scan_bsum<<<1, 256, 0, stream>>>(bsum, nbs);
    scan_final<<<nbs, 256, 0, stream>>>(cnt, bsum, M_);
    scatter_pairs<<<nb, 256, 0, stream>>>(ei, cnt, pairs, E, N, nb, NBK);
    fine_sort<<<NBK, 256, 0, stream>>>(pairs, cnt, offs, ssrc, E, N, nb, NBK);

    // dtype prep (merged conv + weight prep)
    int n4 = N * 32;
    prep_all<<<(n4 + 131072 + 255) / 256, 256, 0, stream>>>(
        (const float4*)x, (uint2*)Hx, n4,
        Wl0, Wr0, Wl1, Wr1, Wl2, Wr2, Wc0, Wc1, Wc2);

    dim3 g1((N + 31) / 32, 1);

    // fused mean-aggregate + GEMM per layer
    fused_gemm<128, true, false, false><<<g1, 256, 0, stream>>>(
        Hx, offs, ssrc, Wc0, bl0, Ha, nullptr, N);
    fused_gemm<128, true, false, false><<<g1, 256, 0, stream>>>(
        Ha, offs, ssrc, Wc1, bl1, Hb, nullptr, N);
    // layer 2: fused kernel does cols 0..127 and writes the mean to Mb once;
    // plain gemm reuses Mb for cols 128..255.
    fused_gemm<256, false, true, true><<<g1, 256, 0, stream>>>(
        Hb, offs, ssrc, Wc2, bl2, d_out, Mb, N);
    gemm_mfma<256, false, true><<<g1, 256, 0, stream>>>(
        Mb, Hb, Wc2 + 128 * 256, bl2 + 128, d_out, N, 128);
}

// Round 10
// 326.021 us; speedup vs baseline: 1.4342x; 1.4342x over previous
//
#include <hip/hip_runtime.h>
#include <stdint.h>

typedef unsigned short u16;
typedef unsigned int   u32;
typedef __attribute__((ext_vector_type(8))) short short8;
typedef __attribute__((ext_vector_type(4))) float f32x4;

#define CHUNK 8192   // edges per block in hist/scatter phases

__device__ __forceinline__ u16 f2bf(float f) {
    u32 u = __float_as_uint(f);
    u32 r = (u + 0x7FFFu + ((u >> 16) & 1u)) >> 16;   // RNE
    return (u16)r;
}

// int64-stored-raw edge_index has every high 32-bit word zero (vals < 2^17).
__device__ __forceinline__ int edge_is64(const int* __restrict__ ei) {
    return ((ei[1] | ei[3] | ei[5] | ei[7] | ei[9] | ei[11]) == 0) ? 1 : 0;
}

__global__ void zero_out(float* __restrict__ p, size_t n) {
    size_t i = (size_t)blockIdx.x * 256 + threadIdx.x;
    size_t stride = (size_t)gridDim.x * 256;
    for (; i < n; i += stride) p[i] = 0.f;
}

// ---------------------------------------------------------------------------
// Phase 1: per-block histogram over coarse buckets (dst >> 8).
// ---------------------------------------------------------------------------
__global__ void hist_bucket(const int* __restrict__ ei, int* __restrict__ cnt,
                            int E, int N, int nb, int NBK) {
    __shared__ int h[256];
    int b = blockIdx.x, t = threadIdx.x;
    h[t] = 0;
    __syncthreads();
    int is64 = edge_is64(ei);
    int base = b * CHUNK;
    int endE = min(base + CHUNK, E);
    for (int i = base + t; i < endE; i += 256) {
        int dst = is64 ? ei[2 * E + 2 * i] : ei[E + i];
        dst = min(max(dst, 0), N - 1);
        atomicAdd(&h[dst >> 8], 1);
    }
    __syncthreads();
    for (int B = t; B < NBK; B += 256) cnt[B * nb + b] = h[B];
}

// ---------------------------------------------------------------------------
// Hierarchical exclusive scan (in place) over int array a[M].
// ---------------------------------------------------------------------------
__global__ void scan_partial(const int* __restrict__ a, int* __restrict__ bsum, int M) {
    __shared__ int sh[256];
    int t = threadIdx.x;
    int idx0 = blockIdx.x * 1024 + t * 4;
    int s = 0;
    #pragma unroll
    for (int i = 0; i < 4; ++i) { int idx = idx0 + i; if (idx < M) s += a[idx]; }
    sh[t] = s;
    __syncthreads();
    #pragma unroll
    for (int off = 128; off > 0; off >>= 1) {
        if (t < off) sh[t] += sh[t + off];
        __syncthreads();
    }
    if (t == 0) bsum[blockIdx.x] = sh[0];
}

__global__ void scan_bsum(int* __restrict__ bsum, int nbs) {
    __shared__ int sh[256];
    __shared__ int carry;
    int t = threadIdx.x;
    if (t == 0) carry = 0;
    __syncthreads();
    for (int base = 0; base < nbs; base += 256) {
        int v = (base + t < nbs) ? bsum[base + t] : 0;
        sh[t] = v;
        __syncthreads();
        #pragma unroll
        for (int off = 1; off < 256; off <<= 1) {
            int x = (t >= off) ? sh[t - off] : 0;
            __syncthreads();
            sh[t] += x;
            __syncthreads();
        }
        if (base + t < nbs) bsum[base + t] = carry + sh[t] - v;
        __syncthreads();
        if (t == 255) carry += sh[255];
        __syncthreads();
    }
}

__global__ void scan_final(int* __restrict__ a, const int* __restrict__ bsum, int M) {
    __shared__ int sh[256];
    int t = threadIdx.x;
    int idx0 = blockIdx.x * 1024 + t * 4;
    int v[4];
    int s = 0;
    #pragma unroll
    for (int i = 0; i < 4; ++i) {
        int idx = idx0 + i;
        v[i] = (idx < M) ? a[idx] : 0;
        s += v[i];
    }
    sh[t] = s;
    __syncthreads();
    #pragma unroll
    for (int off = 1; off < 256; off <<= 1) {
        int x = (t >= off) ? sh[t - off] : 0;
        __syncthreads();
        sh[t] += x;
        __syncthreads();
    }
    int run = sh[t] - s + bsum[blockIdx.x];
    #pragma unroll
    for (int i = 0; i < 4; ++i) {
        int idx = idx0 + i;
        if (idx < M) a[idx] = run;
        run += v[i];
    }
}

// ---------------------------------------------------------------------------
// Phase 3: scatter packed edges (src | (dst&255)<<17) into per-(block,bucket)
// exclusive regions. LDS cursors -> dense block-private global writes.
// ---------------------------------------------------------------------------
__global__ void scatter_pairs(const int* __restrict__ ei, const int* __restrict__ pboff,
                              u32* __restrict__ pairs, int E, int N, int nb, int NBK) {
    __shared__ int cur[256];
    int b = blockIdx.x, t = threadIdx.x;
    for (int B = t; B < NBK; B += 256) cur[B] = pboff[B * nb + b];
    __syncthreads();
    int is64 = edge_is64(ei);
    int base = b * CHUNK;
    int endE = min(base + CHUNK, E);
    for (int i = base + t; i < endE; i += 256) {
        int src = is64 ? ei[2 * i] : ei[i];
        int dst = is64 ? ei[2 * E + 2 * i] : ei[E + i];
        src = min(max(src, 0), N - 1);
        dst = min(max(dst, 0), N - 1);
        int slot = atomicAdd(&cur[dst >> 8], 1);
        pairs[slot] = (u32)src | ((u32)(dst & 255) << 17);
    }
}

// ---------------------------------------------------------------------------
// Phase 4: per-bucket counting sort (256 nodes). Writes offs[] and CSR ssrc.
// ---------------------------------------------------------------------------
__global__ void fine_sort(const u32* __restrict__ pairs, const int* __restrict__ pboff,
                          int* __restrict__ offs, int* __restrict__ ssrc,
                          int E, int N, int nb, int NBK) {
    __shared__ int hist[256];
    __shared__ int excl[256];
    __shared__ int cur[256];
    int B = blockIdx.x, t = threadIdx.x;
    if (B == 0 && t == 0) offs[N] = E;
    int rs = pboff[B * nb];
    int re = (B + 1 < NBK) ? pboff[(B + 1) * nb] : E;
    hist[t] = 0;
    __syncthreads();
    for (int i = rs + t; i < re; i += 256) {
        u32 p = pairs[i];
        atomicAdd(&hist[(p >> 17) & 255], 1);
    }
    __syncthreads();
    int v = hist[t];
    excl[t] = v;
    __syncthreads();
    #pragma unroll
    for (int off = 1; off < 256; off <<= 1) {
        int x = (t >= off) ? excl[t - off] : 0;
        __syncthreads();
        excl[t] += x;
        __syncthreads();
    }
    int ex = excl[t] - v;
    int node = B * 256 + t;
    if (node < N) offs[node] = rs + ex;
    cur[t] = rs + ex;
    __syncthreads();
    for (int i = rs + t; i < re; i += 256) {
        u32 p = pairs[i];
        int slot = atomicAdd(&cur[(p >> 17) & 255], 1);
        ssrc[slot] = (int)(p & 0x1FFFFu);
    }
}

// ---------------------------------------------------------------------------
// dtype prep: x->bf16 conversion and weight concat+convert, merged into one
// dispatch (independent work; saves a launch).
// ---------------------------------------------------------------------------
__global__ void prep_all(const float4* __restrict__ x, uint2* __restrict__ H, int n4,
                         const float* __restrict__ Wl0, const float* __restrict__ Wr0,
                         const float* __restrict__ Wl1, const float* __restrict__ Wr1,
                         const float* __restrict__ Wl2, const float* __restrict__ Wr2,
                         u16* __restrict__ Wc0, u16* __restrict__ Wc1,
                         u16* __restrict__ Wc2) {
    int i = blockIdx.x * 256 + threadIdx.x;
    if (i < n4) {
        float4 v = x[i];
        uint2 o;
        o.x = ((u32)f2bf(v.y) << 16) | f2bf(v.x);
        o.y = ((u32)f2bf(v.w) << 16) | f2bf(v.z);
        H[i] = o;
        return;
    }
    int k = i - n4;                      // 0 .. 131071 weight elems
    if (k >= 131072) return;
    const float* Wl; const float* Wr; u16* Wc; int base;
    if (k < 32768)      { Wl = Wl0; Wr = Wr0; Wc = Wc0; base = k; }
    else if (k < 65536) { Wl = Wl1; Wr = Wr1; Wc = Wc1; base = k - 32768; }
    else                { Wl = Wl2; Wr = Wr2; Wc = Wc2; base = k - 65536; }
    int j = base >> 8, kk = base & 255;
    float v = (kk < 128) ? Wl[j * 128 + kk] : Wr[j * 128 + (kk - 128)];
    Wc[base] = f2bf(v);
}

__device__ __forceinline__ void acc8(float* a, uint4 p) {
    a[0] += __uint_as_float(p.x << 16); a[1] += __uint_as_float(p.x & 0xFFFF0000u);
    a[2] += __uint_as_float(p.y << 16); a[3] += __uint_as_float(p.y & 0xFFFF0000u);
    a[4] += __uint_as_float(p.z << 16); a[5] += __uint_as_float(p.z & 0xFFFF0000u);
    a[6] += __uint_as_float(p.w << 16); a[7] += __uint_as_float(p.w & 0xFFFF0000u);
}

// ---------------------------------------------------------------------------
// FUSED layer kernel (round-10): round-9 showed (256,8) spills (VGPR cap 64
// -> 230 MB scratch traffic, 2x slower) and revealed round-7's real limiter:
// GRID STARVATION, not launch bounds (VGPR=48/LDS 16.9 KB already allowed
// 8 blocks/CU; the grid only supplied 6.1). Fix: halve the tile to 16 rows
// -> 3125 blocks (12.2/CU), LDS 8.4 KB, one node per 16-lane group (single
// cursor), per-block gather work halves so the straggler tail shortens.
// Codegen restored to the known-good (256,4). Total MFMA work unchanged
// (16 MFMAs/wave vs 32, 2x blocks); B panel refetch is L2-hot.
// ---------------------------------------------------------------------------
template<int DOUT, bool RELU, bool OUT_F32, bool WRITE_MEAN>
__global__ __launch_bounds__(256, 4)
void fused_gemm(const u16* __restrict__ H, const int* __restrict__ offs,
                const int* __restrict__ ssrc, const u16* __restrict__ Wc,
                const float* __restrict__ bias, void* __restrict__ out,
                u16* __restrict__ Mb, int N) {
    constexpr int OSMB = OUT_F32 ? (16 * 132 * 4) : (16 * 136 * 2);
    constexpr int ASMB = 2 * 16 * 128 * 2;                // 8 KB A-tile
    constexpr int SMB  = (ASMB > OSMB) ? ASMB : OSMB;
    __shared__ __align__(16) char smem[SMB];
    u16* ldsA0 = (u16*)smem;               // mean half [16][128]
    u16* ldsA1 = (u16*)smem + 16 * 128;    // H half    [16][128]

    int tid = threadIdx.x;
    int w   = tid >> 6;               // wave id 0..3 -> 32-col slice
    int l   = tid & 63;
    int lr  = l & 15;
    int lq  = l >> 4;
    int kof = lq * 8;

    int mb0 = blockIdx.x * 16;        // row tile base (16 rows)
    int nc  = w * 32;                 // this wave's col base (slab-relative)

    // ---- (1) H-tile DMA into ldsA1: 256 chunks, 1 per thread ----
    {
        const u16* gH = H + (size_t)mb0 * 128;   // 4 KB contiguous
        int c  = tid;                            // LDS chunk 0..255 (16 B units)
        int r  = c >> 4;                         // row 0..15
        int jj = c & 15;                         // LDS chunk-in-row
        int gj = jj ^ (r & 15);                  // inverse-swizzled global chunk
        __builtin_amdgcn_global_load_lds(
            (const u32*)(gH + (size_t)(r * 16 + gj) * 8),
            (u32*)(ldsA1 + (size_t)c * 8), 16, 0, 0);
    }

    // ---- (2) gather-aggregate: one node per 16-lane group ----
    {
        int g   = tid >> 4;           // group 0..15 -> local row g
        int sub = tid & 15;           // 8 dims per lane
        int node = mb0 + g;
        if (node < N) {
            int beg = offs[node], end = offs[node + 1];
            float a0[8] = {}, a1[8] = {}, a2[8] = {}, a3[8] = {};
            int j = beg;
            for (; j + 3 < end; j += 4) {
                int s0 = ssrc[j], s1 = ssrc[j + 1], s2 = ssrc[j + 2], s3 = ssrc[j + 3];
                uint4 p0 = *(const uint4*)(H + (size_t)s0 * 128 + sub * 8);
                uint4 p1 = *(const uint4*)(H + (size_t)s1 * 128 + sub * 8);
                uint4 p2 = *(const uint4*)(H + (size_t)s2 * 128 + sub * 8);
                uint4 p3 = *(const uint4*)(H + (size_t)s3 * 128 + sub * 8);
                acc8(a0, p0); acc8(a1, p1); acc8(a2, p2); acc8(a3, p3);
            }
            for (; j < end; ++j) {
                uint4 p0 = *(const uint4*)(H + (size_t)ssrc[j] * 128 + sub * 8);
                acc8(a0, p0);
            }
            int d = end - beg;
            float sc = 1.f / (float)(d > 0 ? d : 1);
            #pragma unroll
            for (int i = 0; i < 8; ++i) a0[i] = (a0[i] + a1[i] + a2[i] + a3[i]) * sc;
            uint4 o;
            o.x = ((u32)f2bf(a0[1]) << 16) | f2bf(a0[0]);
            o.y = ((u32)f2bf(a0[3]) << 16) | f2bf(a0[2]);
            o.z = ((u32)f2bf(a0[5]) << 16) | f2bf(a0[4]);
            o.w = ((u32)f2bf(a0[7]) << 16) | f2bf(a0[6]);
            int jx = sub ^ (g & 15);              // swizzled chunk-in-row
            *(uint4*)(ldsA0 + ((size_t)g * 16 + jx) * 8) = o;
            if (WRITE_MEAN)
                *(uint4*)(Mb + (size_t)node * 128 + sub * 8) = o;
        }
    }

    // ---- (3) B panel into registers (L2-resident, short liveness) ----
    short8 b0[8], b1[8];
    #pragma unroll
    for (int ks = 0; ks < 8; ++ks) {
        int kb = ks * 32 + kof;
        b0[ks] = *(const short8*)(Wc + (size_t)(nc + lr) * 256 + kb);
        b1[ks] = *(const short8*)(Wc + (size_t)(nc + 16 + lr) * 256 + kb);
    }
    float bv0 = bias[nc + lr];
    float bv1 = bias[nc + 16 + lr];

    __syncthreads();   // drains DMA (vmcnt) + mean ds_writes (lgkm)

    // ---- (4) MFMA: A frags from LDS (swizzled), B from regs ----
    f32x4 acc[2];
    acc[0] = (f32x4){0.f, 0.f, 0.f, 0.f};
    acc[1] = (f32x4){0.f, 0.f, 0.f, 0.f};

    #pragma unroll
    for (int ks = 0; ks < 8; ++ks) {
        const u16* hb = (ks < 4) ? ldsA0 : ldsA1;
        int j0 = (ks & 3) * 4 + lq;              // chunk-in-row this frag needs
        int jx = j0 ^ lr;                        // swizzled LDS chunk
        short8 a = *(const short8*)(hb + ((size_t)lr * 16 + jx) * 8);
        acc[0] = __builtin_amdgcn_mfma_f32_16x16x32_bf16(a, b0[ks], acc[0], 0, 0, 0);
        acc[1] = __builtin_amdgcn_mfma_f32_16x16x32_bf16(a, b1[ks], acc[1], 0, 0, 0);
    }

    __syncthreads();   // A-tile reads done -> safe to reuse smem for epilogue

    // ---- epilogue: bias/relu -> LDS tile (union) -> coalesced stores ----
    if (OUT_F32) {
        float* sm = (float*)smem;                 // [16][132] padded
        #pragma unroll
        for (int ct = 0; ct < 2; ++ct) {
            int cl = w * 32 + ct * 16 + lr;
            float bv = ct ? bv1 : bv0;
            #pragma unroll
            for (int i = 0; i < 4; ++i) {
                int rl = lq * 4 + i;
                float v = acc[ct][i] + bv;
                if (RELU) v = fmaxf(v, 0.f);
                sm[rl * 132 + cl] = v;
            }
        }
        __syncthreads();
        // 16 rows x 128 f32 = 512 float4 chunks, 2 per thread
        #pragma unroll
        for (int c = 0; c < 2; ++c) {
            int chunk = c * 256 + tid;
            int rr = chunk >> 5, cc = chunk & 31;
            int row = mb0 + rr;
            if (row < N) {
                float4 v = *(const float4*)(sm + rr * 132 + cc * 4);
                *(float4*)((float*)out + (size_t)row * DOUT + cc * 4) = v;
            }
        }
    } else {
        u16* sm = (u16*)smem;                     // [16][136] padded
        #pragma unroll
        for (int ct = 0; ct < 2; ++ct) {
            int cl = w * 32 + ct * 16 + lr;
            float bv = ct ? bv1 : bv0;
            #pragma unroll
            for (int i = 0; i < 4; ++i) {
                int rl = lq * 4 + i;
                float v = acc[ct][i] + bv;
                if (RELU) v = fmaxf(v, 0.f);
                sm[rl * 136 + cl] = f2bf(v);
            }
        }
        __syncthreads();
        // 16 rows x 128 bf16 = 256 uint4 chunks, 1 per thread
        {
            int rr = tid >> 4, cc = tid & 15;
            int row = mb0 + rr;
            if (row < N) {
                uint4 v = *(const uint4*)(sm + rr * 136 + cc * 8);
                *(uint4*)((u16*)out + (size_t)row * DOUT + cc * 8) = v;
            }
        }
    }
}

// ---------------------------------------------------------------------------
// Plain MFMA GEMM (16-row tile), used only for layer-2 cols 128..255:
// reads the mean from Mb (written once by the fused kernel).
// ---------------------------------------------------------------------------
template<int DOUT, bool RELU, bool OUT_F32>
__global__ __launch_bounds__(256, 4)
void gemm_mfma(const u16* __restrict__ M, const u16* __restrict__ H,
               const u16* __restrict__ Wc, const float* __restrict__ bias,
               void* __restrict__ out, int N, int noff) {
    constexpr int OSMB = OUT_F32 ? (16 * 132 * 4) : (16 * 136 * 2);
    constexpr int ASMB = 2 * 16 * 128 * 2;
    constexpr int SMB  = (ASMB > OSMB) ? ASMB : OSMB;
    __shared__ __align__(16) char smem[SMB];
    u16* ldsA0 = (u16*)smem;
    u16* ldsA1 = (u16*)smem + 16 * 128;

    int tid = threadIdx.x;
    int w   = tid >> 6;
    int l   = tid & 63;
    int lr  = l & 15;
    int lq  = l >> 4;
    int kof = lq * 8;

    int mb0 = blockIdx.x * 16;
    int nc  = w * 32;

    // ---- A-tile DMA into LDS (both halves, 1 chunk each per thread) ----
    {
        const u16* gM = M + (size_t)mb0 * 128;
        const u16* gH = H + (size_t)mb0 * 128;
        int c  = tid;
        int r  = c >> 4;
        int jj = c & 15;
        int gj = jj ^ (r & 15);
        __builtin_amdgcn_global_load_lds(
            (const u32*)(gM + (size_t)(r * 16 + gj) * 8),
            (u32*)(ldsA0 + (size_t)c * 8), 16, 0, 0);
        __builtin_amdgcn_global_load_lds(
            (const u32*)(gH + (size_t)(r * 16 + gj) * 8),
            (u32*)(ldsA1 + (size_t)c * 8), 16, 0, 0);
    }

    // ---- B panel into registers ----
    short8 b0[8], b1[8];
    #pragma unroll
    for (int ks = 0; ks < 8; ++ks) {
        int kb = ks * 32 + kof;
        b0[ks] = *(const short8*)(Wc + (size_t)(nc + lr) * 256 + kb);
        b1[ks] = *(const short8*)(Wc + (size_t)(nc + 16 + lr) * 256 + kb);
    }
    float bv0 = bias[nc + lr];
    float bv1 = bias[nc + 16 + lr];

    __syncthreads();

    f32x4 acc[2];
    acc[0] = (f32x4){0.f, 0.f, 0.f, 0.f};
    acc[1] = (f32x4){0.f, 0.f, 0.f, 0.f};

    #pragma unroll
    for (int ks = 0; ks < 8; ++ks) {
        const u16* hb = (ks < 4) ? ldsA0 : ldsA1;
        int j0 = (ks & 3) * 4 + lq;
        int jx = j0 ^ lr;
        short8 a = *(const short8*)(hb + ((size_t)lr * 16 + jx) * 8);
        acc[0] = __builtin_amdgcn_mfma_f32_16x16x32_bf16(a, b0[ks], acc[0], 0, 0, 0);
        acc[1] = __builtin_amdgcn_mfma_f32_16x16x32_bf16(a, b1[ks], acc[1], 0, 0, 0);
    }

    __syncthreads();   // A-tile reads done -> reuse smem for epilogue

    if (OUT_F32) {
        float* sm = (float*)smem;
        #pragma unroll
        for (int ct = 0; ct < 2; ++ct) {
            int cl = w * 32 + ct * 16 + lr;
            float bv = ct ? bv1 : bv0;
            #pragma unroll
            for (int i = 0; i < 4; ++i) {
                int rl = lq * 4 + i;
                float v = acc[ct][i] + bv;
                if (RELU) v = fmaxf(v, 0.f);
                sm[rl * 132 + cl] = v;
            }
        }
        __syncthreads();
        #pragma unroll
        for (int c = 0; c < 2; ++c) {
            int chunk = c * 256 + tid;
            int rr = chunk >> 5, cc = chunk & 31;
            int row = mb0 + rr;
            if (row < N) {
                float4 v = *(const float4*)(sm + rr * 132 + cc * 4);
                *(float4*)((float*)out + (size_t)row * DOUT + noff + cc * 4) = v;
            }
        }
    } else {
        u16* sm = (u16*)smem;
        #pragma unroll
        for (int ct = 0; ct < 2; ++ct) {
            int cl = w * 32 + ct * 16 + lr;
            float bv = ct ? bv1 : bv0;
            #pragma unroll
            for (int i = 0; i < 4; ++i) {
                int rl = lq * 4 + i;
                float v = acc[ct][i] + bv;
                if (RELU) v = fmaxf(v, 0.f);
                sm[rl * 136 + cl] = f2bf(v);
            }
        }
        __syncthreads();
        {
            int rr = tid >> 4, cc = tid & 15;
            int row = mb0 + rr;
            if (row < N) {
                uint4 v = *(const uint4*)(sm + rr * 136 + cc * 8);
                *(uint4*)((u16*)out + (size_t)row * DOUT + noff + cc * 8) = v;
            }
        }
    }
}

extern "C" void kernel_launch(void* const* d_in, const int* in_sizes, int n_in,
                              void* d_out, int out_size, void* d_ws, size_t ws_size,
                              hipStream_t stream) {
    const float* x   = (const float*)d_in[0];
    const int*   ei  = (const int*)d_in[1];
    const float* Wl0 = (const float*)d_in[2];
    const float* bl0 = (const float*)d_in[3];
    const float* Wr0 = (const float*)d_in[4];
    const float* Wl1 = (const float*)d_in[5];
    const float* bl1 = (const float*)d_in[6];
    const float* Wr1 = (const float*)d_in[7];
    const float* Wl2 = (const float*)d_in[8];
    const float* bl2 = (const float*)d_in[9];
    const float* Wr2 = (const float*)d_in[10];

    const int N = in_sizes[0] / 128;
    const int E = in_sizes[1] / 2;

    const int NBK = (N + 255) >> 8;
    const int nb  = (E + CHUNK - 1) / CHUNK;
    const int M_  = NBK * nb;
    const int nbs = (M_ + 1023) / 1024;

    size_t off = 0;
    auto alloc = [&](size_t bytes) -> size_t {
        size_t p = off;
        off += (bytes + 255) & ~(size_t)255;
        return p;
    };
    size_t o_cnt   = alloc((size_t)M_ * 4);
    size_t o_bsum  = alloc((size_t)nbs * 4);
    size_t o_offs  = alloc(((size_t)N + 1) * 4);
    size_t o_ssrc  = alloc((size_t)E * 4);
    size_t o_pairs = alloc((size_t)E * 4);
    size_t o_Hx    = alloc((size_t)N * 128 * 2);
    size_t o_Ha    = alloc((size_t)N * 128 * 2);
    size_t o_Hb    = alloc((size_t)N * 128 * 2);
    size_t o_Mb    = alloc((size_t)N * 128 * 2);
    size_t o_Wc0   = alloc((size_t)128 * 256 * 2);
    size_t o_Wc1   = alloc((size_t)128 * 256 * 2);
    size_t o_Wc2   = alloc((size_t)256 * 256 * 2);

    if (off > ws_size || NBK > 256 || N > (1 << 17)) {
        zero_out<<<2048, 256, 0, stream>>>((float*)d_out, (size_t)out_size);
        return;
    }

    char* ws = (char*)d_ws;
    int*  cnt   = (int*)(ws + o_cnt);
    int*  bsum  = (int*)(ws + o_bsum);
    int*  offs  = (int*)(ws + o_offs);
    int*  ssrc  = (int*)(ws + o_ssrc);
    u32*  pairs = (u32*)(ws + o_pairs);
    u16*  Hx    = (u16*)(ws + o_Hx);
    u16*  Ha    = (u16*)(ws + o_Ha);
    u16*  Hb    = (u16*)(ws + o_Hb);
    u16*  Mb    = (u16*)(ws + o_Mb);
    u16*  Wc0   = (u16*)(ws + o_Wc0);
    u16*  Wc1   = (u16*)(ws + o_Wc1);
    u16*  Wc2   = (u16*)(ws + o_Wc2);

    // CSR build: hist -> scan -> block-private scatter -> per-bucket sort
    hist_bucket<<<nb, 256, 0, stream>>>(ei, cnt, E, N, nb, NBK);
    scan_partial<<<nbs, 256, 0, stream>>>(cnt, bsum, M_);
    scan_bsum<<<1, 256, 0, stream>>>(bsum, nbs);
    scan_final<<<nbs, 256, 0, stream>>>(cnt, bsum, M_);
    scatter_pairs<<<nb, 256, 0, stream>>>(ei, cnt, pairs, E, N, nb, NBK);
    fine_sort<<<NBK, 256, 0, stream>>>(pairs, cnt, offs, ssrc, E, N, nb, NBK);

    // dtype prep (merged conv + weight prep)
    int n4 = N * 32;
    prep_all<<<(n4 + 131072 + 255) / 256, 256, 0, stream>>>(
        (const float4*)x, (uint2*)Hx, n4,
        Wl0, Wr0, Wl1, Wr1, Wl2, Wr2, Wc0, Wc1, Wc2);

    dim3 g1((N + 15) / 16, 1);

    // fused mean-aggregate + GEMM per layer
    fused_gemm<128, true, false, false><<<g1, 256, 0, stream>>>(
        Hx, offs, ssrc, Wc0, bl0, Ha, nullptr, N);
    fused_gemm<128, true, false, false><<<g1, 256, 0, stream>>>(
        Ha, offs, ssrc, Wc1, bl1, Hb, nullptr, N);
    // layer 2: fused kernel does cols 0..127 and writes the mean to Mb once;
    // plain gemm reuses Mb for cols 128..255.
    fused_gemm<256, false, true, true><<<g1, 256, 0, stream>>>(
        Hb, offs, ssrc, Wc2, bl2, d_out, Mb, N);
    gemm_mfma<256, false, true><<<g1, 256, 0, stream>>>(
        Mb, Hb, Wc2 + 128 * 256, bl2 + 128, d_out, N, 128);
}

// Round 11
// 293.975 us; speedup vs baseline: 1.5906x; 1.1090x over previous
//
#include <hip/hip_runtime.h>
#include <stdint.h>

typedef unsigned short u16;
typedef unsigned int   u32;
typedef __attribute__((ext_vector_type(8))) short short8;
typedef __attribute__((ext_vector_type(4))) float f32x4;

#define CHUNK 8192   // edges per block in hist/scatter phases

__device__ __forceinline__ u16 f2bf(float f) {
    u32 u = __float_as_uint(f);
    u32 r = (u + 0x7FFFu + ((u >> 16) & 1u)) >> 16;   // RNE
    return (u16)r;
}

// int64-stored-raw edge_index has every high 32-bit word zero (vals < 2^17).
__device__ __forceinline__ int edge_is64(const int* __restrict__ ei) {
    return ((ei[1] | ei[3] | ei[5] | ei[7] | ei[9] | ei[11]) == 0) ? 1 : 0;
}

__global__ void zero_out(float* __restrict__ p, size_t n) {
    size_t i = (size_t)blockIdx.x * 256 + threadIdx.x;
    size_t stride = (size_t)gridDim.x * 256;
    for (; i < n; i += stride) p[i] = 0.f;
}

// ---------------------------------------------------------------------------
// Phase 1: per-block histogram over coarse buckets (dst >> 8).
// ---------------------------------------------------------------------------
__global__ void hist_bucket(const int* __restrict__ ei, int* __restrict__ cnt,
                            int E, int N, int nb, int NBK) {
    __shared__ int h[256];
    int b = blockIdx.x, t = threadIdx.x;
    h[t] = 0;
    __syncthreads();
    int is64 = edge_is64(ei);
    int base = b * CHUNK;
    int endE = min(base + CHUNK, E);
    for (int i = base + t; i < endE; i += 256) {
        int dst = is64 ? ei[2 * E + 2 * i] : ei[E + i];
        dst = min(max(dst, 0), N - 1);
        atomicAdd(&h[dst >> 8], 1);
    }
    __syncthreads();
    for (int B = t; B < NBK; B += 256) cnt[B * nb + b] = h[B];
}

// ---------------------------------------------------------------------------
// Hierarchical exclusive scan (in place) over int array a[M].
// ---------------------------------------------------------------------------
__global__ void scan_partial(const int* __restrict__ a, int* __restrict__ bsum, int M) {
    __shared__ int sh[256];
    int t = threadIdx.x;
    int idx0 = blockIdx.x * 1024 + t * 4;
    int s = 0;
    #pragma unroll
    for (int i = 0; i < 4; ++i) { int idx = idx0 + i; if (idx < M) s += a[idx]; }
    sh[t] = s;
    __syncthreads();
    #pragma unroll
    for (int off = 128; off > 0; off >>= 1) {
        if (t < off) sh[t] += sh[t + off];
        __syncthreads();
    }
    if (t == 0) bsum[blockIdx.x] = sh[0];
}

__global__ void scan_bsum(int* __restrict__ bsum, int nbs) {
    __shared__ int sh[256];
    __shared__ int carry;
    int t = threadIdx.x;
    if (t == 0) carry = 0;
    __syncthreads();
    for (int base = 0; base < nbs; base += 256) {
        int v = (base + t < nbs) ? bsum[base + t] : 0;
        sh[t] = v;
        __syncthreads();
        #pragma unroll
        for (int off = 1; off < 256; off <<= 1) {
            int x = (t >= off) ? sh[t - off] : 0;
            __syncthreads();
            sh[t] += x;
            __syncthreads();
        }
        if (base + t < nbs) bsum[base + t] = carry + sh[t] - v;
        __syncthreads();
        if (t == 255) carry += sh[255];
        __syncthreads();
    }
}

__global__ void scan_final(int* __restrict__ a, const int* __restrict__ bsum, int M) {
    __shared__ int sh[256];
    int t = threadIdx.x;
    int idx0 = blockIdx.x * 1024 + t * 4;
    int v[4];
    int s = 0;
    #pragma unroll
    for (int i = 0; i < 4; ++i) {
        int idx = idx0 + i;
        v[i] = (idx < M) ? a[idx] : 0;
        s += v[i];
    }
    sh[t] = s;
    __syncthreads();
    #pragma unroll
    for (int off = 1; off < 256; off <<= 1) {
        int x = (t >= off) ? sh[t - off] : 0;
        __syncthreads();
        sh[t] += x;
        __syncthreads();
    }
    int run = sh[t] - s + bsum[blockIdx.x];
    #pragma unroll
    for (int i = 0; i < 4; ++i) {
        int idx = idx0 + i;
        if (idx < M) a[idx] = run;
        run += v[i];
    }
}

// ---------------------------------------------------------------------------
// Phase 3: scatter packed edges (src | (dst&255)<<17) into per-(block,bucket)
// exclusive regions. LDS cursors -> dense block-private global writes.
// ---------------------------------------------------------------------------
__global__ void scatter_pairs(const int* __restrict__ ei, const int* __restrict__ pboff,
                              u32* __restrict__ pairs, int E, int N, int nb, int NBK) {
    __shared__ int cur[256];
    int b = blockIdx.x, t = threadIdx.x;
    for (int B = t; B < NBK; B += 256) cur[B] = pboff[B * nb + b];
    __syncthreads();
    int is64 = edge_is64(ei);
    int base = b * CHUNK;
    int endE = min(base + CHUNK, E);
    for (int i = base + t; i < endE; i += 256) {
        int src = is64 ? ei[2 * i] : ei[i];
        int dst = is64 ? ei[2 * E + 2 * i] : ei[E + i];
        src = min(max(src, 0), N - 1);
        dst = min(max(dst, 0), N - 1);
        int slot = atomicAdd(&cur[dst >> 8], 1);
        pairs[slot] = (u32)src | ((u32)(dst & 255) << 17);
    }
}

// ---------------------------------------------------------------------------
// Phase 4: per-bucket counting sort (256 nodes). Writes offs[] and CSR ssrc.
// ---------------------------------------------------------------------------
__global__ void fine_sort(const u32* __restrict__ pairs, const int* __restrict__ pboff,
                          int* __restrict__ offs, int* __restrict__ ssrc,
                          int E, int N, int nb, int NBK) {
    __shared__ int hist[256];
    __shared__ int excl[256];
    __shared__ int cur[256];
    int B = blockIdx.x, t = threadIdx.x;
    if (B == 0 && t == 0) offs[N] = E;
    int rs = pboff[B * nb];
    int re = (B + 1 < NBK) ? pboff[(B + 1) * nb] : E;
    hist[t] = 0;
    __syncthreads();
    for (int i = rs + t; i < re; i += 256) {
        u32 p = pairs[i];
        atomicAdd(&hist[(p >> 17) & 255], 1);
    }
    __syncthreads();
    int v = hist[t];
    excl[t] = v;
    __syncthreads();
    #pragma unroll
    for (int off = 1; off < 256; off <<= 1) {
        int x = (t >= off) ? excl[t - off] : 0;
        __syncthreads();
        excl[t] += x;
        __syncthreads();
    }
    int ex = excl[t] - v;
    int node = B * 256 + t;
    if (node < N) offs[node] = rs + ex;
    cur[t] = rs + ex;
    __syncthreads();
    for (int i = rs + t; i < re; i += 256) {
        u32 p = pairs[i];
        int slot = atomicAdd(&cur[(p >> 17) & 255], 1);
        ssrc[slot] = (int)(p & 0x1FFFFu);
    }
}

// ---------------------------------------------------------------------------
// dtype prep: x->bf16 conversion and weight concat+convert, merged into one
// dispatch (independent work; saves a launch).
// ---------------------------------------------------------------------------
__global__ void prep_all(const float4* __restrict__ x, uint2* __restrict__ H, int n4,
                         const float* __restrict__ Wl0, const float* __restrict__ Wr0,
                         const float* __restrict__ Wl1, const float* __restrict__ Wr1,
                         const float* __restrict__ Wl2, const float* __restrict__ Wr2,
                         u16* __restrict__ Wc0, u16* __restrict__ Wc1,
                         u16* __restrict__ Wc2) {
    int i = blockIdx.x * 256 + threadIdx.x;
    if (i < n4) {
        float4 v = x[i];
        uint2 o;
        o.x = ((u32)f2bf(v.y) << 16) | f2bf(v.x);
        o.y = ((u32)f2bf(v.w) << 16) | f2bf(v.z);
        H[i] = o;
        return;
    }
    int k = i - n4;                      // 0 .. 131071 weight elems
    if (k >= 131072) return;
    const float* Wl; const float* Wr; u16* Wc; int base;
    if (k < 32768)      { Wl = Wl0; Wr = Wr0; Wc = Wc0; base = k; }
    else if (k < 65536) { Wl = Wl1; Wr = Wr1; Wc = Wc1; base = k - 32768; }
    else                { Wl = Wl2; Wr = Wr2; Wc = Wc2; base = k - 65536; }
    int j = base >> 8, kk = base & 255;
    float v = (kk < 128) ? Wl[j * 128 + kk] : Wr[j * 128 + (kk - 128)];
    Wc[base] = f2bf(v);
}

__device__ __forceinline__ void acc8(float* a, uint4 p) {
    a[0] += __uint_as_float(p.x << 16); a[1] += __uint_as_float(p.x & 0xFFFF0000u);
    a[2] += __uint_as_float(p.y << 16); a[3] += __uint_as_float(p.y & 0xFFFF0000u);
    a[4] += __uint_as_float(p.z << 16); a[5] += __uint_as_float(p.z & 0xFFFF0000u);
    a[6] += __uint_as_float(p.w << 16); a[7] += __uint_as_float(p.w & 0xFFFF0000u);
}

// ---------------------------------------------------------------------------
// FUSED layer kernel (round-11): r6/r7/r10 all show ~3 blocks/CU resident
// (occupancy 33-41%) regardless of grid size and LDS — and all used
// 256-thread blocks. If block residency/CU is the pinned quantity, waves/CU
// is set by waves-per-BLOCK. This round: same 32-row tile and B traffic as
// round 7 (best: 300.7 us), but 512-thread / 8-wave blocks: 32 lane-groups
// (one node per group, single proven cursor), 8 waves x 16-col B slices
// (32 B-VGPRs/wave), 512-wide DMA + epilogue. Resident waves should ~2x.
// __launch_bounds__(512,4) keeps the same 128-VGPR cap that gave spill-free
// 44-48 VGPR in rounds 7/10.
// ---------------------------------------------------------------------------
template<int DOUT, bool RELU, bool OUT_F32, bool WRITE_MEAN>
__global__ __launch_bounds__(512, 4)
void fused_gemm(const u16* __restrict__ H, const int* __restrict__ offs,
                const int* __restrict__ ssrc, const u16* __restrict__ Wc,
                const float* __restrict__ bias, void* __restrict__ out,
                u16* __restrict__ Mb, int N) {
    constexpr int OSMB = OUT_F32 ? (32 * 132 * 4) : (32 * 136 * 2);
    constexpr int ASMB = 2 * 32 * 128 * 2;                // 16 KB A-tile
    constexpr int SMB  = (ASMB > OSMB) ? ASMB : OSMB;
    __shared__ __align__(16) char smem[SMB];
    u16* ldsA0 = (u16*)smem;               // mean half [32][128]
    u16* ldsA1 = (u16*)smem + 32 * 128;    // H half    [32][128]

    int tid = threadIdx.x;
    int w   = tid >> 6;               // wave id 0..7 -> 16-col slice
    int l   = tid & 63;
    int lr  = l & 15;
    int lq  = l >> 4;
    int kof = lq * 8;

    int mb0 = blockIdx.x * 32;        // row tile base (32 rows)
    int nc  = w * 16;                 // this wave's col base (slab-relative)

    // ---- (1) H-tile DMA into ldsA1: 512 chunks, 1 per thread ----
    {
        const u16* gH = H + (size_t)mb0 * 128;   // 8 KB contiguous
        int c  = tid;                            // LDS chunk 0..511 (16 B units)
        int r  = c >> 4;                         // row 0..31
        int jj = c & 15;                         // LDS chunk-in-row
        int gj = jj ^ (r & 15);                  // inverse-swizzled global chunk
        __builtin_amdgcn_global_load_lds(
            (const u32*)(gH + (size_t)(r * 16 + gj) * 8),
            (u32*)(ldsA1 + (size_t)c * 8), 16, 0, 0);
    }

    // ---- (2) gather-aggregate: one node per 16-lane group (32 groups) ----
    {
        int g   = tid >> 4;           // group 0..31 -> local row g
        int sub = tid & 15;           // 8 dims per lane
        int node = mb0 + g;
        if (node < N) {
            int beg = offs[node], end = offs[node + 1];
            float a0[8] = {}, a1[8] = {}, a2[8] = {}, a3[8] = {};
            int j = beg;
            for (; j + 3 < end; j += 4) {
                int s0 = ssrc[j], s1 = ssrc[j + 1], s2 = ssrc[j + 2], s3 = ssrc[j + 3];
                uint4 p0 = *(const uint4*)(H + (size_t)s0 * 128 + sub * 8);
                uint4 p1 = *(const uint4*)(H + (size_t)s1 * 128 + sub * 8);
                uint4 p2 = *(const uint4*)(H + (size_t)s2 * 128 + sub * 8);
                uint4 p3 = *(const uint4*)(H + (size_t)s3 * 128 + sub * 8);
                acc8(a0, p0); acc8(a1, p1); acc8(a2, p2); acc8(a3, p3);
            }
            for (; j < end; ++j) {
                uint4 p0 = *(const uint4*)(H + (size_t)ssrc[j] * 128 + sub * 8);
                acc8(a0, p0);
            }
            int d = end - beg;
            float sc = 1.f / (float)(d > 0 ? d : 1);
            #pragma unroll
            for (int i = 0; i < 8; ++i) a0[i] = (a0[i] + a1[i] + a2[i] + a3[i]) * sc;
            uint4 o;
            o.x = ((u32)f2bf(a0[1]) << 16) | f2bf(a0[0]);
            o.y = ((u32)f2bf(a0[3]) << 16) | f2bf(a0[2]);
            o.z = ((u32)f2bf(a0[5]) << 16) | f2bf(a0[4]);
            o.w = ((u32)f2bf(a0[7]) << 16) | f2bf(a0[6]);
            int jx = sub ^ (g & 15);              // swizzled chunk-in-row
            *(uint4*)(ldsA0 + ((size_t)g * 16 + jx) * 8) = o;
            if (WRITE_MEAN)
                *(uint4*)(Mb + (size_t)node * 128 + sub * 8) = o;
        }
    }

    // ---- (3) B panel into registers: 16 cols per wave (8 short8) ----
    short8 b0[8];
    #pragma unroll
    for (int ks = 0; ks < 8; ++ks) {
        int kb = ks * 32 + kof;
        b0[ks] = *(const short8*)(Wc + (size_t)(nc + lr) * 256 + kb);
    }
    float bv0 = bias[nc + lr];

    __syncthreads();   // drains DMA (vmcnt) + mean ds_writes (lgkm)

    // ---- (4) MFMA: 2 row-frags x 1 col-frag per wave = 16 MFMAs ----
    f32x4 acc[2];
    acc[0] = (f32x4){0.f, 0.f, 0.f, 0.f};
    acc[1] = (f32x4){0.f, 0.f, 0.f, 0.f};

    #pragma unroll
    for (int ks = 0; ks < 8; ++ks) {
        const u16* hb = (ks < 4) ? ldsA0 : ldsA1;
        int j0 = (ks & 3) * 4 + lq;              // chunk-in-row this frag needs
        int jx = j0 ^ lr;                        // swizzled LDS chunk
        short8 a0 = *(const short8*)(hb + ((size_t)lr * 16 + jx) * 8);
        short8 a1 = *(const short8*)(hb + ((size_t)(lr + 16) * 16 + jx) * 8);
        acc[0] = __builtin_amdgcn_mfma_f32_16x16x32_bf16(a0, b0[ks], acc[0], 0, 0, 0);
        acc[1] = __builtin_amdgcn_mfma_f32_16x16x32_bf16(a1, b0[ks], acc[1], 0, 0, 0);
    }

    __syncthreads();   // A-tile reads done -> safe to reuse smem for epilogue

    // ---- epilogue: bias/relu -> LDS tile (union) -> coalesced stores ----
    if (OUT_F32) {
        float* sm = (float*)smem;                 // [32][132] padded
        int cl = w * 16 + lr;
        #pragma unroll
        for (int rg = 0; rg < 2; ++rg) {
            #pragma unroll
            for (int i = 0; i < 4; ++i) {
                int rl = rg * 16 + lq * 4 + i;
                float v = acc[rg][i] + bv0;
                if (RELU) v = fmaxf(v, 0.f);
                sm[rl * 132 + cl] = v;
            }
        }
        __syncthreads();
        // 32 rows x 128 f32 = 1024 float4 chunks, 2 per thread
        #pragma unroll
        for (int c = 0; c < 2; ++c) {
            int chunk = c * 512 + tid;
            int rr = chunk >> 5, cc = chunk & 31;
            int row = mb0 + rr;
            if (row < N) {
                float4 v = *(const float4*)(sm + rr * 132 + cc * 4);
                *(float4*)((float*)out + (size_t)row * DOUT + cc * 4) = v;
            }
        }
    } else {
        u16* sm = (u16*)smem;                     // [32][136] padded
        int cl = w * 16 + lr;
        #pragma unroll
        for (int rg = 0; rg < 2; ++rg) {
            #pragma unroll
            for (int i = 0; i < 4; ++i) {
                int rl = rg * 16 + lq * 4 + i;
                float v = acc[rg][i] + bv0;
                if (RELU) v = fmaxf(v, 0.f);
                sm[rl * 136 + cl] = f2bf(v);
            }
        }
        __syncthreads();
        // 32 rows x 128 bf16 = 512 uint4 chunks, 1 per thread
        {
            int rr = tid >> 4, cc = tid & 15;
            int row = mb0 + rr;
            if (row < N) {
                uint4 v = *(const uint4*)(sm + rr * 136 + cc * 8);
                *(uint4*)((u16*)out + (size_t)row * DOUT + cc * 8) = v;
            }
        }
    }
}

// ---------------------------------------------------------------------------
// Plain MFMA GEMM (round-7 structure, 256 threads, 32-row tile), used only
// for layer-2 cols 128..255: reads the mean from Mb.
// ---------------------------------------------------------------------------
template<int DOUT, bool RELU, bool OUT_F32>
__global__ __launch_bounds__(256, 4)
void gemm_mfma(const u16* __restrict__ M, const u16* __restrict__ H,
               const u16* __restrict__ Wc, const float* __restrict__ bias,
               void* __restrict__ out, int N, int noff) {
    constexpr int OSMB = OUT_F32 ? (32 * 132 * 4) : (32 * 136 * 2);
    constexpr int ASMB = 2 * 32 * 128 * 2;
    constexpr int SMB  = (ASMB > OSMB) ? ASMB : OSMB;
    __shared__ __align__(16) char smem[SMB];
    u16* ldsA0 = (u16*)smem;
    u16* ldsA1 = (u16*)smem + 32 * 128;

    int tid = threadIdx.x;
    int w   = tid >> 6;
    int l   = tid & 63;
    int lr  = l & 15;
    int lq  = l >> 4;
    int kof = lq * 8;

    int mb0 = blockIdx.x * 32;
    int nc  = w * 32;

    // ---- A-tile DMA into LDS ----
    {
        const u16* gM = M + (size_t)mb0 * 128;
        const u16* gH = H + (size_t)mb0 * 128;
        #pragma unroll
        for (int p = 0; p < 2; ++p) {
            int c  = p * 256 + tid;
            int r  = c >> 4;
            int jj = c & 15;
            int gj = jj ^ (r & 15);
            __builtin_amdgcn_global_load_lds(
                (const u32*)(gM + (size_t)(r * 16 + gj) * 8),
                (u32*)(ldsA0 + (size_t)c * 8), 16, 0, 0);
            __builtin_amdgcn_global_load_lds(
                (const u32*)(gH + (size_t)(r * 16 + gj) * 8),
                (u32*)(ldsA1 + (size_t)c * 8), 16, 0, 0);
        }
    }

    // ---- B panel into registers ----
    short8 b0[8], b1[8];
    #pragma unroll
    for (int ks = 0; ks < 8; ++ks) {
        int kb = ks * 32 + kof;
        b0[ks] = *(const short8*)(Wc + (size_t)(nc + lr) * 256 + kb);
        b1[ks] = *(const short8*)(Wc + (size_t)(nc + 16 + lr) * 256 + kb);
    }
    float bv0 = bias[nc + lr];
    float bv1 = bias[nc + 16 + lr];

    __syncthreads();

    f32x4 acc[2][2];
    #pragma unroll
    for (int i = 0; i < 2; ++i)
        #pragma unroll
        for (int j = 0; j < 2; ++j) acc[i][j] = (f32x4){0.f, 0.f, 0.f, 0.f};

    #pragma unroll
    for (int ks = 0; ks < 8; ++ks) {
        const u16* hb = (ks < 4) ? ldsA0 : ldsA1;
        int j0 = (ks & 3) * 4 + lq;
        int jx = j0 ^ lr;
        short8 a0 = *(const short8*)(hb + ((size_t)lr * 16 + jx) * 8);
        short8 a1 = *(const short8*)(hb + ((size_t)(lr + 16) * 16 + jx) * 8);
        acc[0][0] = __builtin_amdgcn_mfma_f32_16x16x32_bf16(a0, b0[ks], acc[0][0], 0, 0, 0);
        acc[0][1] = __builtin_amdgcn_mfma_f32_16x16x32_bf16(a0, b1[ks], acc[0][1], 0, 0, 0);
        acc[1][0] = __builtin_amdgcn_mfma_f32_16x16x32_bf16(a1, b0[ks], acc[1][0], 0, 0, 0);
        acc[1][1] = __builtin_amdgcn_mfma_f32_16x16x32_bf16(a1, b1[ks], acc[1][1], 0, 0, 0);
    }

    __syncthreads();   // A-tile reads done -> reuse smem for epilogue

    if (OUT_F32) {
        float* sm = (float*)smem;
        #pragma unroll
        for (int ct = 0; ct < 2; ++ct) {
            int cl = w * 32 + ct * 16 + lr;
            float bv = ct ? bv1 : bv0;
            #pragma unroll
            for (int rg = 0; rg < 2; ++rg) {
                #pragma unroll
                for (int i = 0; i < 4; ++i) {
                    int rl = rg * 16 + lq * 4 + i;
                    float v = acc[rg][ct][i] + bv;
                    if (RELU) v = fmaxf(v, 0.f);
                    sm[rl * 132 + cl] = v;
                }
            }
        }
        __syncthreads();
        #pragma unroll
        for (int c = 0; c < 4; ++c) {
            int chunk = c * 256 + tid;
            int rr = chunk >> 5, cc = chunk & 31;
            int row = mb0 + rr;
            if (row < N) {
                float4 v = *(const float4*)(sm + rr * 132 + cc * 4);
                *(float4*)((float*)out + (size_t)row * DOUT + noff + cc * 4) = v;
            }
        }
    } else {
        u16* sm = (u16*)smem;
        #pragma unroll
        for (int ct = 0; ct < 2; ++ct) {
            int cl = w * 32 + ct * 16 + lr;
            float bv = ct ? bv1 : bv0;
            #pragma unroll
            for (int rg = 0; rg < 2; ++rg) {
                #pragma unroll
                for (int i = 0; i < 4; ++i) {
                    int rl = rg * 16 + lq * 4 + i;
                    float v = acc[rg][ct][i] + bv;
                    if (RELU) v = fmaxf(v, 0.f);
                    sm[rl * 136 + cl] = f2bf(v);
                }
            }
        }
        __syncthreads();
        #pragma unroll
        for (int c = 0; c < 2; ++c) {
            int chunk = c * 256 + tid;
            int rr = chunk >> 4, cc = chunk & 15;
            int row = mb0 + rr;
            if (row < N) {
                uint4 v = *(const uint4*)(sm + rr * 136 + cc * 8);
                *(uint4*)((u16*)out + (size_t)row * DOUT + noff + cc * 8) = v;
            }
        }
    }
}

extern "C" void kernel_launch(void* const* d_in, const int* in_sizes, int n_in,
                              void* d_out, int out_size, void* d_ws, size_t ws_size,
                              hipStream_t stream) {
    const float* x   = (const float*)d_in[0];
    const int*   ei  = (const int*)d_in[1];
    const float* Wl0 = (const float*)d_in[2];
    const float* bl0 = (const float*)d_in[3];
    const float* Wr0 = (const float*)d_in[4];
    const float* Wl1 = (const float*)d_in[5];
    const float* bl1 = (const float*)d_in[6];
    const float* Wr1 = (const float*)d_in[7];
    const float* Wl2 = (const float*)d_in[8];
    const float* bl2 = (const float*)d_in[9];
    const float* Wr2 = (const float*)d_in[10];

    const int N = in_sizes[0] / 128;
    const int E = in_sizes[1] / 2;

    const int NBK = (N + 255) >> 8;
    const int nb  = (E + CHUNK - 1) / CHUNK;
    const int M_  = NBK * nb;
    const int nbs = (M_ + 1023) / 1024;

    size_t off = 0;
    auto alloc = [&](size_t bytes) -> size_t {
        size_t p = off;
        off += (bytes + 255) & ~(size_t)255;
        return p;
    };
    size_t o_cnt   = alloc((size_t)M_ * 4);
    size_t o_bsum  = alloc((size_t)nbs * 4);
    size_t o_offs  = alloc(((size_t)N + 1) * 4);
    size_t o_ssrc  = alloc((size_t)E * 4);
    size_t o_pairs = alloc((size_t)E * 4);
    size_t o_Hx    = alloc((size_t)N * 128 * 2);
    size_t o_Ha    = alloc((size_t)N * 128 * 2);
    size_t o_Hb    = alloc((size_t)N * 128 * 2);
    size_t o_Mb    = alloc((size_t)N * 128 * 2);
    size_t o_Wc0   = alloc((size_t)128 * 256 * 2);
    size_t o_Wc1   = alloc((size_t)128 * 256 * 2);
    size_t o_Wc2   = alloc((size_t)256 * 256 * 2);

    if (off > ws_size || NBK > 256 || N > (1 << 17)) {
        zero_out<<<2048, 256, 0, stream>>>((float*)d_out, (size_t)out_size);
        return;
    }

    char* ws = (char*)d_ws;
    int*  cnt   = (int*)(ws + o_cnt);
    int*  bsum  = (int*)(ws + o_bsum);
    int*  offs  = (int*)(ws + o_offs);
    int*  ssrc  = (int*)(ws + o_ssrc);
    u32*  pairs = (u32*)(ws + o_pairs);
    u16*  Hx    = (u16*)(ws + o_Hx);
    u16*  Ha    = (u16*)(ws + o_Ha);
    u16*  Hb    = (u16*)(ws + o_Hb);
    u16*  Mb    = (u16*)(ws + o_Mb);
    u16*  Wc0   = (u16*)(ws + o_Wc0);
    u16*  Wc1   = (u16*)(ws + o_Wc1);
    u16*  Wc2   = (u16*)(ws + o_Wc2);

    // CSR build: hist -> scan -> block-private scatter -> per-bucket sort
    hist_bucket<<<nb, 256, 0, stream>>>(ei, cnt, E, N, nb, NBK);
    scan_partial<<<nbs, 256, 0, stream>>>(cnt, bsum, M_);
    scan_bsum<<<1, 256, 0, stream>>>(bsum, nbs);
    scan_final<<<nbs, 256, 0, stream>>>(cnt, bsum, M_);
    scatter_pairs<<<nb, 256, 0, stream>>>(ei, cnt, pairs, E, N, nb, NBK);
    fine_sort<<<NBK, 256, 0, stream>>>(pairs, cnt, offs, ssrc, E, N, nb, NBK);

    // dtype prep (merged conv + weight prep)
    int n4 = N * 32;
    prep_all<<<(n4 + 131072 + 255) / 256, 256, 0, stream>>>(
        (const float4*)x, (uint2*)Hx, n4,
        Wl0, Wr0, Wl1, Wr1, Wl2, Wr2, Wc0, Wc1, Wc2);

    dim3 g1((N + 31) / 32, 1);

    // fused mean-aggregate + GEMM per layer (512-thread blocks)
    fused_gemm<128, true, false, false><<<g1, 512, 0, stream>>>(
        Hx, offs, ssrc, Wc0, bl0, Ha, nullptr, N);
    fused_gemm<128, true, false, false><<<g1, 512, 0, stream>>>(
        Ha, offs, ssrc, Wc1, bl1, Hb, nullptr, N);
    // layer 2: fused kernel does cols 0..127 and writes the mean to Mb once;
    // plain gemm reuses Mb for cols 128..255.
    fused_gemm<256, false, true, true><<<g1, 512, 0, stream>>>(
        Hb, offs, ssrc, Wc2, bl2, d_out, Mb, N);
    gemm_mfma<256, false, true><<<g1, 256, 0, stream>>>(
        Mb, Hb, Wc2 + 128 * 256, bl2 + 128, d_out, N, 128);
}